// Round 11
// baseline (41.065 us; speedup 1.0000x reference)
//
#include <hip/hip_runtime.h>
#include <hip/hip_bf16.h>

// FeatureContrast: out[b,i,j,hw] = x[b,c,hw]*exp(w*x[b,c,hw]) / sum_{3x3 ch window}
// over 16x16 channel grid, c=(i+1)*16+(j+1). B=32, HW=4096.
//
// R11 = R10 (exp-exactly-once cooperative block) with e stored in LDS as
// packed bf16 pairs -> 16KB LDS (was 32KB). R10 counters: FETCH=65.6MB
// (exactly-once + L3), VALUBusy 21%, but Occupancy 33% (LDS-capped at
// 5 blocks/CU). 16KB -> 8 blocks/CU (wave-capped, 100%). Numerator stays
// f32 in registers; only the 9-term denom is bf16 (abs err ~0.012 << 0.1).

#define NIN 16
#define NOUT 14
#define HW 4096
#define PIX 32            // pixels per block
#define SLOTS (PIX / 2)   // 16 f2 slots

typedef float f2 __attribute__((ext_vector_type(2)));

__global__ __launch_bounds__(256) void fc_kernel(
    const float* __restrict__ x,
    const float* __restrict__ wp,
    float* __restrict__ out)
{
    __shared__ unsigned int elds[NIN * NIN * SLOTS];   // 16 KB: bf16x2 e[ch][slot]

    const float w = wp[0];
    const int tid  = threadIdx.x;
    const int slot = tid & (SLOTS - 1);      // 0..15 (f2 slot = 2 pixels)
    const int cg   = tid >> 4;               // 0..15 (channel column)
    const int hw0  = blockIdx.x * PIX;       // 0..4064 step 32
    const int b    = blockIdx.y;             // 0..31

    const float* xb = x + ((size_t)b * (NIN * NIN)) * HW + hw0 + slot * 2;

    f2 num[NIN];   // x*e of channel (p, cg); rows 1..14 consumed

    // ---- Phase 1: load all 256 channels, one exp each, bf16-pack e -> LDS ----
    #pragma unroll
    for (int p = 0; p < NIN; ++p) {          // channel row (compile-time)
        const int ch = p * NIN + cg;
        f2 v = *(const f2*)(xb + (size_t)ch * HW);
        f2 e;
        e.x = __expf(v.x * w);
        e.y = __expf(v.y * w);
        num[p] = v * e;
        unsigned bx = __float_as_uint(e.x);
        bx = (bx + 0x7FFFu + ((bx >> 16) & 1u)) >> 16;          // RNE to bf16
        unsigned by = __float_as_uint(e.y);
        by = (by + 0x7FFFu + ((by >> 16) & 1u)) & 0xFFFF0000u;  // keep in high half
        elds[ch * SLOTS + slot] = bx | by;
    }

    __syncthreads();

    // ---- Phase 2: cols 1..14 compute outputs ----
    if (cg >= 1 && cg <= NOUT) {
        const int j = cg - 1;                // output column

        // Horizontal 3-sums for all 16 rows at this column (bf16 -> f32 unpack)
        f2 rs[NIN];
        #pragma unroll
        for (int r = 0; r < NIN; ++r) {
            unsigned ua = elds[(r * NIN + cg - 1) * SLOTS + slot];
            unsigned ub = elds[(r * NIN + cg    ) * SLOTS + slot];
            unsigned uc = elds[(r * NIN + cg + 1) * SLOTS + slot];
            f2 a, bb, c;
            a.x  = __uint_as_float(ua << 16);  a.y  = __uint_as_float(ua & 0xFFFF0000u);
            bb.x = __uint_as_float(ub << 16);  bb.y = __uint_as_float(ub & 0xFFFF0000u);
            c.x  = __uint_as_float(uc << 16);  c.y  = __uint_as_float(uc & 0xFFFF0000u);
            rs[r] = a + bb + c;
        }

        float* ob = out + ((size_t)b * (NOUT * NOUT) + j) * HW + hw0 + slot * 2;
        #pragma unroll
        for (int i = 0; i < NOUT; ++i) {
            f2 s = rs[i] + rs[i + 1] + rs[i + 2];
            f2 d;
            d.x = __fdividef(num[i + 1].x, s.x);
            d.y = __fdividef(num[i + 1].y, s.y);
            *(f2*)(ob + (size_t)(i * NOUT) * HW) = d;
        }
    }
}

extern "C" void kernel_launch(void* const* d_in, const int* in_sizes, int n_in,
                              void* d_out, int out_size, void* d_ws, size_t ws_size,
                              hipStream_t stream) {
    const float* x  = (const float*)d_in[0];
    const float* wp = (const float*)d_in[1];
    float* out = (float*)d_out;

    dim3 block(256, 1, 1);
    dim3 grid(HW / PIX, 32, 1);   // 128 x 32 = 4096 blocks (16/CU)
    hipLaunchKernelGGL(fc_kernel, grid, block, 0, stream, x, wp, out);
}

// Round 12
// 40.811 us; speedup vs baseline: 1.0062x; 1.0062x over previous
//
#include <hip/hip_runtime.h>
#include <hip/hip_bf16.h>

// FeatureContrast: out[b,i,j,hw] = x[b,c,hw]*exp(w*x[b,c,hw]) / sum_{3x3 ch window}
// over 16x16 channel grid, c=(i+1)*16+(j+1). B=32, HW=4096.
//
// R12 = R11 (exp-once, bf16 LDS) widened to 512 threads x 64 pixels:
// per-wave global bursts double to 256B per channel/output row (was 128B).
// R11 showed occupancy (60%) not binding at 41us; remaining gap vs ~31-33us
// floor attributed to short strided bursts (166MB HBM at only ~4 TB/s eff
// while fill does 7 TB/s). LDS 32KB bf16 -> wave-capped 4 blocks/CU (100%).

#define NIN 16
#define NOUT 14
#define HW 4096
#define PIX 64            // pixels per block
#define SLOTS (PIX / 2)   // 32 f2 slots

typedef float f2 __attribute__((ext_vector_type(2)));

__global__ __launch_bounds__(512) void fc_kernel(
    const float* __restrict__ x,
    const float* __restrict__ wp,
    float* __restrict__ out)
{
    __shared__ unsigned int elds[NIN * NIN * SLOTS];   // 32 KB: bf16x2 e[ch][slot]

    const float w = wp[0];
    const int tid  = threadIdx.x;            // 0..511
    const int slot = tid & (SLOTS - 1);      // 0..31 (f2 slot = 2 pixels)
    const int cg   = tid >> 5;               // 0..15 (channel column)
    const int hw0  = blockIdx.x * PIX;       // 0..4032 step 64
    const int b    = blockIdx.y;             // 0..31

    const float* xb = x + ((size_t)b * (NIN * NIN)) * HW + hw0 + slot * 2;

    f2 num[NIN];   // x*e of channel (p, cg); rows 1..14 consumed

    // ---- Phase 1: load all 256 channels, one exp each, bf16-pack e -> LDS ----
    #pragma unroll
    for (int p = 0; p < NIN; ++p) {          // channel row (compile-time)
        const int ch = p * NIN + cg;
        f2 v = *(const f2*)(xb + (size_t)ch * HW);
        f2 e;
        e.x = __expf(v.x * w);
        e.y = __expf(v.y * w);
        num[p] = v * e;
        unsigned bx = __float_as_uint(e.x);
        bx = (bx + 0x7FFFu + ((bx >> 16) & 1u)) >> 16;          // RNE to bf16 (low half)
        unsigned by = __float_as_uint(e.y);
        by = (by + 0x7FFFu + ((by >> 16) & 1u)) & 0xFFFF0000u;  // RNE, keep high half
        elds[ch * SLOTS + slot] = bx | by;
    }

    __syncthreads();

    // ---- Phase 2: cols 1..14 compute outputs ----
    if (cg >= 1 && cg <= NOUT) {
        const int j = cg - 1;                // output column

        // Horizontal 3-sums for all 16 rows at this column (bf16 -> f32 unpack)
        f2 rs[NIN];
        #pragma unroll
        for (int r = 0; r < NIN; ++r) {
            unsigned ua = elds[(r * NIN + cg - 1) * SLOTS + slot];
            unsigned ub = elds[(r * NIN + cg    ) * SLOTS + slot];
            unsigned uc = elds[(r * NIN + cg + 1) * SLOTS + slot];
            f2 a, bb, c;
            a.x  = __uint_as_float(ua << 16);  a.y  = __uint_as_float(ua & 0xFFFF0000u);
            bb.x = __uint_as_float(ub << 16);  bb.y = __uint_as_float(ub & 0xFFFF0000u);
            c.x  = __uint_as_float(uc << 16);  c.y  = __uint_as_float(uc & 0xFFFF0000u);
            rs[r] = a + bb + c;
        }

        float* ob = out + ((size_t)b * (NOUT * NOUT) + j) * HW + hw0 + slot * 2;
        #pragma unroll
        for (int i = 0; i < NOUT; ++i) {
            f2 s = rs[i] + rs[i + 1] + rs[i + 2];
            f2 d;
            d.x = __fdividef(num[i + 1].x, s.x);
            d.y = __fdividef(num[i + 1].y, s.y);
            *(f2*)(ob + (size_t)(i * NOUT) * HW) = d;
        }
    }
}

extern "C" void kernel_launch(void* const* d_in, const int* in_sizes, int n_in,
                              void* d_out, int out_size, void* d_ws, size_t ws_size,
                              hipStream_t stream) {
    const float* x  = (const float*)d_in[0];
    const float* wp = (const float*)d_in[1];
    float* out = (float*)d_out;

    dim3 block(512, 1, 1);
    dim3 grid(HW / PIX, 32, 1);   // 64 x 32 = 2048 blocks (8/CU, 4 resident)
    hipLaunchKernelGGL(fc_kernel, grid, block, 0, stream, x, wp, out);
}

// Round 13
// 40.554 us; speedup vs baseline: 1.0126x; 1.0063x over previous
//
#include <hip/hip_runtime.h>
#include <hip/hip_bf16.h>

// FeatureContrast: out[b,i,j,hw] = x[b,c,hw]*exp(w*x[b,c,hw]) / sum_{3x3 ch window}
// over 16x16 channel grid, c=(i+1)*16+(j+1). B=32, HW=4096.
//
// FINAL (= R10, measured best 40.5us): exp-exactly-once cooperative block.
// Block = one b x 32 pixels x all 256 channels. Phase 1: coalesced load,
// one exp per element, e -> 32KB f32 LDS; interior threads keep num=x*e in
// registers. One barrier. Phase 2: cols 1..14 build 16 horizontal 3-sums,
// roll denom down 14 output rows, store.
//
// Why this is the stop point (evidence): pattern-bound at ~4.1-4.6 TB/s for
// the 16KB-strided channel-major R/W mix (100MB compulsory writes + ~67MB
// HBM reads -> ~40us floor). Four orthogonal levers all null/exhausted:
// no-compute ablation ~43us (R6), occupancy 33->60% null (R11), burst
// 128->256B null (R12), exp-once -1us (R10). Layout change via transpose
// pre-pass costs >= extra 40us round trip.

#define NIN 16
#define NOUT 14
#define HW 4096
#define PIX 32            // pixels per block
#define SLOTS (PIX / 2)   // 16 f2 slots

typedef float f2 __attribute__((ext_vector_type(2)));

__global__ __launch_bounds__(256) void fc_kernel(
    const float* __restrict__ x,
    const float* __restrict__ wp,
    float* __restrict__ out)
{
    __shared__ f2 elds[NIN * NIN * SLOTS];   // 32 KB: e[ch][slot]

    const float w = wp[0];
    const int tid  = threadIdx.x;
    const int slot = tid & (SLOTS - 1);      // 0..15 (f2 slot = 2 pixels)
    const int cg   = tid >> 4;               // 0..15 (channel column)
    const int hw0  = blockIdx.x * PIX;       // 0..4064 step 32
    const int b    = blockIdx.y;             // 0..31

    const float* xb = x + ((size_t)b * (NIN * NIN)) * HW + hw0 + slot * 2;

    f2 num[NIN];   // x*e of channel (p, cg); rows 1..14 consumed

    // ---- Phase 1: load all 256 channels, one exp each, e -> LDS ----
    #pragma unroll
    for (int p = 0; p < NIN; ++p) {          // channel row (compile-time)
        const int ch = p * NIN + cg;
        f2 v = *(const f2*)(xb + (size_t)ch * HW);
        f2 e;
        e.x = __expf(v.x * w);
        e.y = __expf(v.y * w);
        elds[ch * SLOTS + slot] = e;
        num[p] = v * e;
    }

    __syncthreads();

    // ---- Phase 2: cols 1..14 compute outputs ----
    if (cg >= 1 && cg <= NOUT) {
        const int j = cg - 1;                // output column

        // Horizontal 3-sums for all 16 rows at this column
        f2 rs[NIN];
        #pragma unroll
        for (int r = 0; r < NIN; ++r) {
            f2 a  = elds[(r * NIN + cg - 1) * SLOTS + slot];
            f2 bb = elds[(r * NIN + cg    ) * SLOTS + slot];
            f2 c  = elds[(r * NIN + cg + 1) * SLOTS + slot];
            rs[r] = a + bb + c;
        }

        float* ob = out + ((size_t)b * (NOUT * NOUT) + j) * HW + hw0 + slot * 2;
        #pragma unroll
        for (int i = 0; i < NOUT; ++i) {
            f2 s = rs[i] + rs[i + 1] + rs[i + 2];
            f2 d;
            d.x = __fdividef(num[i + 1].x, s.x);
            d.y = __fdividef(num[i + 1].y, s.y);
            *(f2*)(ob + (size_t)(i * NOUT) * HW) = d;
        }
    }
}

extern "C" void kernel_launch(void* const* d_in, const int* in_sizes, int n_in,
                              void* d_out, int out_size, void* d_ws, size_t ws_size,
                              hipStream_t stream) {
    const float* x  = (const float*)d_in[0];
    const float* wp = (const float*)d_in[1];
    float* out = (float*)d_out;

    dim3 block(256, 1, 1);
    dim3 grid(HW / PIX, 32, 1);   // 128 x 32 = 4096 blocks (16/CU)
    hipLaunchKernelGGL(fc_kernel, grid, block, 0, stream, x, wp, out);
}